// Round 1
// baseline (125.989 us; speedup 1.0000x reference)
//
#include <hip/hip_runtime.h>

// LengthRegulator: B=16, S=512, D=384, MAX_DUR=8 -> max_len=4096
// out[b,t,:] = text_emb[b, searchsorted_right(cumsum(dur[b]), t), :] if t < total else 0

#define BB 16
#define SS 512
#define DD 384
#define D4 (DD / 4)      // 96 float4 per row
#define MAXLEN 4096      // S * MAX_DUR

// ---- kernel 1: per-batch inclusive scan of durations -> cs[B*S] ----
__global__ void lr_cumsum_kernel(const int* __restrict__ dur, int* __restrict__ cs) {
    __shared__ int buf[SS];
    const int b = blockIdx.x;
    const int t = threadIdx.x;
    buf[t] = dur[b * SS + t];
    __syncthreads();
    #pragma unroll
    for (int off = 1; off < SS; off <<= 1) {
        int v = (t >= off) ? buf[t - off] : 0;
        __syncthreads();
        buf[t] += v;
        __syncthreads();
    }
    cs[b * SS + t] = buf[t];
}

// ---- kernel 2: idxmap[b*MAXLEN + t] = source row (or -1 if t >= total) ----
__global__ void lr_idxmap_kernel(const int* __restrict__ cs, int* __restrict__ idxmap) {
    const int i = blockIdx.x * blockDim.x + threadIdx.x;   // i in [0, B*MAXLEN)
    if (i >= BB * MAXLEN) return;
    const int b = i >> 12;           // / MAXLEN
    const int t = i & (MAXLEN - 1);
    const int* c = cs + b * SS;
    const int total = c[SS - 1];
    // searchsorted right: first index with c[idx] > t
    int lo = 0, hi = SS;
    while (lo < hi) {
        int mid = (lo + hi) >> 1;
        if (c[mid] <= t) lo = mid + 1; else hi = mid;
    }
    int idx = lo;
    if (idx > SS - 1) idx = SS - 1;  // clip (matches jnp.clip)
    idxmap[i] = (t < total) ? idx : -1;
}

// ---- kernel 3: gather, one float4 per thread ----
__global__ void lr_gather_kernel(const float4* __restrict__ emb,
                                 const int* __restrict__ idxmap,
                                 float4* __restrict__ out) {
    const int i = blockIdx.x * blockDim.x + threadIdx.x;   // [0, B*MAXLEN*D4)
    const int d4 = i % D4;
    const int bt = i / D4;           // b*MAXLEN + t
    const int b  = bt >> 12;
    const int idx = idxmap[bt];      // broadcast across the 96 lanes sharing bt
    float4 v = make_float4(0.f, 0.f, 0.f, 0.f);
    if (idx >= 0) v = emb[(b * SS + idx) * D4 + d4];
    out[i] = v;
}

extern "C" void kernel_launch(void* const* d_in, const int* in_sizes, int n_in,
                              void* d_out, int out_size, void* d_ws, size_t ws_size,
                              hipStream_t stream) {
    const float* text_emb = (const float*)d_in[0];   // (16,512,384) f32
    const int*   durations = (const int*)d_in[1];    // (16,512) i32
    float* out = (float*)d_out;                      // (16,4096,384) f32

    int* cs     = (int*)d_ws;                        // B*S ints      = 32 KB
    int* idxmap = cs + BB * SS;                      // B*MAXLEN ints = 256 KB

    // 1) cumsum: 16 blocks x 512 threads
    lr_cumsum_kernel<<<BB, SS, 0, stream>>>(durations, cs);

    // 2) idx map: B*MAXLEN = 65536 threads
    {
        const int n = BB * MAXLEN;
        lr_idxmap_kernel<<<(n + 255) / 256, 256, 0, stream>>>(cs, idxmap);
    }

    // 3) gather: B*MAXLEN*D4 = 6,291,456 float4 threads
    {
        const int n4 = BB * MAXLEN * D4;
        lr_gather_kernel<<<(n4 + 255) / 256, 256, 0, stream>>>(
            (const float4*)text_emb, idxmap, (float4*)out);
    }
}